// Round 11
// baseline (152.551 us; speedup 1.0000x reference)
//
#include <hip/hip_runtime.h>
#include <stdint.h>
#include <stddef.h>
#include <math.h>

// SIR scan: B=16384 batches, T=2048 steps, F=2 (beta,gamma), fp32.
// Round 11: DIAGNOSTIC discriminator. R3/R9 machine, 5 passes in one
// launch: pass 0 = full scan (correct output); passes 1-4 = re-scan of
// chunks 16..31 only (134 MB, L3-resident after pass 0), results kept
// live via asm sink (rule #17), not stored.
// Separates: (H1) per-CU VMEM cap (L3-fed passes as slow as HBM-fed ->
// dur ~170us, FETCH ~300MB) vs (H2) HBM-pattern cap (L3-fed passes fast
// -> dur ~110-130us). Also lifts our kernel above the 150us fill-kernel
// wall so its PMC row is finally visible.

#define T_STEPS 2048
#define C_STEPS 64                   // timesteps per chunk
#define NCHUNK  (T_STEPS / C_STEPS)  // 32
#define BPB     64                   // batches per block
#define PAIRS   (C_STEPS / 2)        // 32 float4 slots per batch per chunk
#define IPC     32                   // global_load_lds instrs per 32 KB chunk
#define NPASS   5
#define HALF_C  (NCHUNK / 2)         // 16: passes 1-4 start here

#define INV_POP 1e-6f

__device__ __forceinline__ void stage_chunk(const float* __restrict__ in,
                                            float4* lds, int b0, int c, int lane)
{
    const int hi = lane >> 5;   // 0 or 1
    const int q  = lane & 31;
#pragma unroll
    for (int j = 0; j < IPC; ++j) {
        const int bi = 2 * j + hi;              // batch within block
        const int p  = q ^ (bi & 15);           // swizzled global pair index
        const float* g = in
            + (size_t)(b0 + bi) * (T_STEPS * 2)
            + (size_t)c * (C_STEPS * 2)
            + (size_t)(p * 4);
        float4* l = lds + j * 64;               // 1 KB per instruction, uniform
        __builtin_amdgcn_global_load_lds(
            (__attribute__((address_space(1))) void*)g,
            (__attribute__((address_space(3))) void*)l,
            16, 0, 0);
    }
}

__device__ __forceinline__ void compute_chunk(const float4* lds, int tid,
                                              float& S, float& I, float& rsum)
{
    const int swz = tid & 15;
    const float4* row = lds + tid * PAIRS;
#pragma unroll
    for (int p = 0; p < PAIRS; ++p) {
        const float4 v = row[p ^ swz];   // steps 2p (v.x,v.y), 2p+1 (v.z,v.w)

        float u  = v.x * INV_POP;
        float t1 = u * S;
        float t2 = u * I;
        float w  = fmaf(-v.y, I, I);
        rsum     = fmaf(v.y, I, rsum);
        I = fmaf(I, t1, w);
        S = fmaf(-t2, S, S);

        u  = v.z * INV_POP;
        t1 = u * S;
        t2 = u * I;
        w  = fmaf(-v.w, I, I);
        rsum = fmaf(v.w, I, rsum);
        I = fmaf(I, t1, w);
        S = fmaf(-t2, S, S);
    }
}

#define BAR()    asm volatile("s_barrier" ::: "memory")
#define WAIT32() asm volatile("s_waitcnt vmcnt(32)" ::: "memory")
#define WAIT0()  asm volatile("s_waitcnt vmcnt(0)"  ::: "memory")

__global__ __launch_bounds__(128)
void sir_scan_kernel(const float* __restrict__ in, const float* __restrict__ init,
                     float* __restrict__ out, int half)
{
    // 4 x 32 KB = 128 KB (1 block/CU), statically distinct objects
    __shared__ float4 buf0[BPB * PAIRS];
    __shared__ float4 buf1[BPB * PAIRS];
    __shared__ float4 buf2[BPB * PAIRS];
    __shared__ float4 buf3[BPB * PAIRS];

    const int tid = threadIdx.x;
    const int b0  = blockIdx.x * BPB;

    if (tid < 64) {
        // ------------- consumer wave: zero outstanding VMEM in the loop
        const int gb = b0 + tid;

#pragma unroll 1
        for (int pass = 0; pass < NPASS; ++pass) {
            const int c0 = (pass == 0) ? 0 : HALF_C;   // both == 0 mod 4

            float S  = init[gb * 3 + 0];
            float I  = init[gb * 3 + 1];
            float R0 = init[gb * 3 + 2];
            float rsum = 0.0f;

            // BAR #k <=> "chunk k has landed"; chunk k lives in buf[k%4]
#pragma unroll 1
            for (int c = c0; c < NCHUNK; c += 4) {
                BAR(); compute_chunk(buf0, tid, S, I, rsum);
                BAR(); compute_chunk(buf1, tid, S, I, rsum);
                BAR(); compute_chunk(buf2, tid, S, I, rsum);
                BAR(); compute_chunk(buf3, tid, S, I, rsum);
            }

            const float R = R0 + rsum;
            if (pass == 0) {
                out[gb * 3 + 0] = S;
                out[gb * 3 + 1] = I;
                out[gb * 3 + 2] = R;
                out[half + gb * 3 + 0] = S;
                out[half + gb * 3 + 1] = I;
                out[half + gb * 3 + 2] = R;
            } else {
                // keep diagnostic passes live without storing (rule #17)
                asm volatile("" :: "v"(S), "v"(I), "v"(R));
            }
        }
    } else {
        // ------------- producer wave: all staging + counted waits here
        const int lane = tid - 64;

#pragma unroll 1
        for (int pass = 0; pass < NPASS; ++pass) {
            const int c0 = (pass == 0) ? 0 : HALF_C;

            // prologue: 2 chunks in flight (outstanding == 0 here:
            // previous pass ended with WAIT0)
            stage_chunk(in, buf0, b0, c0 + 0, lane);
            stage_chunk(in, buf1, b0, c0 + 1, lane);

            // chunk x -> buf[x%4] (c0 % 4 == 0 in every pass).
            // Invariant at each WAIT32: outstanding = chunks {c, c+1};
            // vmcnt(32) => chunk c fully landed, c+1 in flight.
#pragma unroll 1
            for (int c = c0; c < NCHUNK - 4; c += 4) {
                WAIT32(); BAR(); stage_chunk(in, buf2, b0, c + 2, lane);
                WAIT32(); BAR(); stage_chunk(in, buf3, b0, c + 3, lane);
                WAIT32(); BAR(); stage_chunk(in, buf0, b0, c + 4, lane);
                WAIT32(); BAR(); stage_chunk(in, buf1, b0, c + 5, lane);
            }
            // last 4 chunks: stage only NCHUNK-2, NCHUNK-1
            WAIT32(); BAR(); stage_chunk(in, buf2, b0, NCHUNK - 2, lane);
            WAIT32(); BAR(); stage_chunk(in, buf3, b0, NCHUNK - 1, lane);
            WAIT32(); BAR();   // chunk NCHUNK-2 landed
            WAIT0();  BAR();   // chunk NCHUNK-1 landed; queue drained
        }
    }
}

extern "C" void kernel_launch(void* const* d_in, const int* in_sizes, int n_in,
                              void* d_out, int out_size, void* d_ws, size_t ws_size,
                              hipStream_t stream) {
    (void)in_sizes; (void)n_in; (void)d_ws; (void)ws_size;
    const float* in   = (const float*)d_in[0];   // (B, T, 2) fp32
    const float* init = (const float*)d_in[1];   // (B, 3)    fp32
    float* out        = (float*)d_out;           // 2 x (B, 3) fp32, concatenated
    const int half = out_size / 2;

    dim3 grid(16384 / BPB);   // 256 blocks, 1 per CU
    dim3 block(128);          // wave 0 = consumer, wave 1 = producer
    sir_scan_kernel<<<grid, block, 0, stream>>>(in, init, out, half);
}